// Round 11
// baseline (2625.096 us; speedup 1.0000x reference)
//
#include <hip/hip_runtime.h>
#include <stdint.h>

#define EPSF 1e-5f
#define MAXNF (1.0f - 1e-5f)

typedef __attribute__((ext_vector_type(8))) short short8;
typedef __attribute__((ext_vector_type(4))) float floatx4;

__device__ __forceinline__ unsigned short f2bf(float f){
  union { float f; uint32_t u; } v; v.f = f;
  return (unsigned short)((v.u + 0x7FFFu + ((v.u >> 16) & 1u)) >> 16);
}
__device__ __forceinline__ float bf_lo(uint32_t u){
  union { uint32_t u; float f; } v; v.u = u << 16; return v.f;
}
__device__ __forceinline__ float bf_hi(uint32_t u){
  union { uint32_t u; float f; } v; v.u = u & 0xffff0000u; return v.f;
}
__device__ __forceinline__ uint32_t cvtpk(float lo, float hi){
  uint32_t r; asm("v_cvt_pk_bf16_f32 %0, %1, %2" : "=v"(r) : "v"(lo), "v"(hi));
  return r;
}
__device__ __forceinline__ float fsqrt(float x){ return __builtin_amdgcn_sqrtf(x); }

__device__ __forceinline__ float4 ld_ball(const unsigned short* rowp, int b){
  const uint2 u = *(const uint2*)(rowp + 4*b);
  return make_float4(bf_lo(u.x), bf_hi(u.x), bf_lo(u.y), bf_hi(u.y));
}
__device__ __forceinline__ void st_ball(unsigned short* rowp, int b, float4 f){
  uint2 u; u.x = cvtpk(f.x, f.y); u.y = cvtpk(f.z, f.w);
  *(uint2*)(rowp + 4*b) = u;
}

__device__ __forceinline__ void gload16(const void* g, void* l){
  __builtin_amdgcn_global_load_lds(
      (__attribute__((address_space(1))) void*)(uintptr_t)g,
      (__attribute__((address_space(3))) void*)l, 16, 0, 0);
}

// ---- fast transcendentals (v_exp/v_log/v_rcp; ~1e-6 rel err vs 1.7e-3 tol) ----
__device__ __forceinline__ float fatanh(float x){
  return 0.5f * __logf(__fdividef(1.f + x, 1.f - x));
}
__device__ __forceinline__ float ftanh_pos(float x){
  const float t = __expf(-2.f * x);
  return __fdividef(1.f - t, 1.f + t);
}
__device__ __forceinline__ float fsig(float x){
  return __fdividef(1.f, 1.f + __expf(-x));
}

__device__ __forceinline__ float wsum(float v){
  #pragma unroll
  for (int o = 32; o; o >>= 1) v += __shfl_xor(v, o);
  return v;
}

// ---------------- per-ball Mobius helpers ----------------
__device__ __forceinline__ float dot4(const float4 a, const float4 b){
  return a.x*b.x + a.y*b.y + a.z*b.z + a.w*b.w;
}
__device__ __forceinline__ float4 scal4(const float4 a, float s){
  return make_float4(a.x*s, a.y*s, a.z*s, a.w*s);
}
__device__ __forceinline__ float clipn(float n){ return fminf(fmaxf(n, EPSF), MAXNF); }

__device__ __forceinline__ float4 mob_add4(const float4 u, const float4 v){
  const float uv = dot4(u,v), uu = dot4(u,u), vv = dot4(v,v);
  const float cu = 1.f + 2.f*uv + vv, cv = 1.f - uu;
  const float inv = __fdividef(1.f, fmaxf(1.f + 2.f*uv + uu*vv, EPSF));
  return make_float4((cu*u.x + cv*v.x)*inv, (cu*u.y + cv*v.y)*inv,
                     (cu*u.z + cv*v.z)*inv, (cu*u.w + cv*v.w)*inv);
}
__device__ __forceinline__ float4 logmap_sig4(const float4 y){
  const float nc = clipn(fsqrt(dot4(y,y)));
  const float s = __fdividef(fatanh(nc), nc);
  return make_float4(fsig(s*y.x), fsig(s*y.y), fsig(s*y.z), fsig(s*y.w));
}
__device__ __forceinline__ float4 mob_pp4(const float4 x, const float4 u){
  const float4 ux = make_float4(u.x*x.x, u.y*x.y, u.z*x.z, u.w*x.w);
  const float xn = clipn(fsqrt(dot4(x,x)));
  const float uxn = fmaxf(fsqrt(dot4(ux,ux)), EPSF);
  const float s = __fdividef(ftanh_pos(__fdividef(uxn, xn) * fatanh(xn)), uxn);
  return scal4(ux, s);
}

// XCD-chunk swizzle for 4096-block row kernels (producer/consumer L2 alignment)
__device__ __forceinline__ int rowswz(int b){ return ((b & 7) << 9) + (b >> 3); }

// -------- fused cast to bf16 + per-row norm, hidden AND x in one dispatch --------
__global__ void cast2_k(const float* __restrict__ H, const float* __restrict__ X,
                        unsigned short* __restrict__ Hbf, unsigned short* __restrict__ Xbf,
                        float* __restrict__ h_n, float* __restrict__ x_n){
  int blk = blockIdx.x;
  const float* src; unsigned short* dst; float* nrm;
  if (blk < 4096){ src = H; dst = Hbf; nrm = h_n; }
  else { src = X; dst = Xbf; nrm = x_n; blk -= 4096; }
  blk = rowswz(blk);
  const int lane = threadIdx.x & 63;
  const int row  = blk*4 + (threadIdx.x >> 6);
  const float4* xr = (const float4*)(src + (size_t)row*1024);
  unsigned short* br_ = dst + (size_t)row*1024;
  float ss = 0.f;
  #pragma unroll
  for (int i = 0; i < 4; ++i){
    const int b = lane + 64*i;
    const float4 v = xr[b];
    st_ball(br_, b, v);
    ss += dot4(v, v);
  }
  ss = wsum(ss);
  if (lane == 0) nrm[row] = fsqrt(ss);
}

// -------- fused weight transpose+cast for all 5 matrices: Wt[n][k]=bf16(W[k][n]) --------
__global__ void wcast5_k(const float* __restrict__ w_z, const float* __restrict__ w_r,
                         const float* __restrict__ u_z, const float* __restrict__ u_r,
                         const float* __restrict__ w_h,
                         unsigned short* __restrict__ wzr, unsigned short* __restrict__ uzr,
                         unsigned short* __restrict__ wht){
  const int m = blockIdx.z;
  const float* W; unsigned short* Wt;
  switch (m){
    case 0: W = w_z; Wt = wzr;           break;
    case 1: W = w_r; Wt = wzr + 1048576; break;
    case 2: W = u_z; Wt = uzr;           break;
    case 3: W = u_r; Wt = uzr + 1048576; break;
    default: W = w_h; Wt = wht;          break;
  }
  __shared__ float tile[32][33];
  const int tx = threadIdx.x, ty = threadIdx.y;     // 32 x 8
  const int k0 = blockIdx.x * 32, n0 = blockIdx.y * 32;
  #pragma unroll
  for (int i = 0; i < 4; ++i)
    tile[ty + i*8][tx] = W[(size_t)(k0 + ty + i*8) * 1024 + n0 + tx];
  __syncthreads();
  #pragma unroll
  for (int i = 0; i < 4; ++i)
    Wt[(size_t)(n0 + ty + i*8) * 1024 + k0 + tx] = f2bf(tile[tx][ty + i*8]);
}

// ====== 256x256 bf16 MFMA GEMM, SINGLE-buffer 64KB LDS -> 2 blocks/CU ======
// Per K-tile: vmcnt(0)+barrier (tile landed) -> ds_read all 24 b128 frags ->
// lgkmcnt(0)+barrier (reads in regs before overwrite) -> stage(t+1) -> 64 MFMA
// (stage HBM latency hides under MFMA intra-block; the co-resident block's
// LDS/MFMA phases interleave inter-block — m114 implicit overlap).
// Chunk swizzle cc^=(row&7) on pre-swizzled source + swizzled ds_read.
#define NT 16
#define BARFENCE do { __builtin_amdgcn_s_barrier(); asm volatile("" ::: "memory"); } while(0)
// A frags for k-slice KS: 8 m-tiles
#define LDAS(dst, KS) do { _Pragma("unroll") for (int m_=0;m_<8;++m_) \
    dst[m_] = *(const short8*)(smem + abase + m_*2048 + (((((KS)<<2)+kg)^x7)<<4)); } while(0)
// B frags for k-slice KS: 4 n-tiles
#define LDBS(dst, KS) do { _Pragma("unroll") for (int n_=0;n_<4;++n_) \
    dst[n_] = *(const short8*)(smem + bbase + n_*2048 + (((((KS)<<2)+kg)^x7)<<4)); } while(0)
#define MM32(AF, BF) do { _Pragma("unroll") for (int m_=0;m_<8;++m_) \
  _Pragma("unroll") for (int n_=0;n_<4;++n_) \
    acc[m_][n_] = __builtin_amdgcn_mfma_f32_16x16x32_bf16(AF[m_], BF[n_], acc[m_][n_], 0,0,0); } while(0)

// A2/Bt2/C2p: second problem (blocks >= nblk1) — merged dual-GEMM dispatch.
__global__ __launch_bounds__(512, 4) void gemm1b_k(const unsigned short* __restrict__ A,
                                                   const unsigned short* __restrict__ Bt,
                                                   unsigned short* __restrict__ C,
                                                   const unsigned short* __restrict__ A2,
                                                   const unsigned short* __restrict__ Bt2,
                                                   unsigned short* __restrict__ C2p,
                                                   int lda, int ldc, int lnx, int nblk1){
  __shared__ unsigned char smem[65536];   // A [0,32K) | B [32K,64K)
  const int tid = threadIdx.x;
  const int lane = tid & 63, w = tid >> 6;
  const int wm = w >> 2, wn = w & 3;
  const int lr = lane & 15, kg = lane >> 4;
  const int x7 = lr & 7;

  int wg = blockIdx.x;
  if (wg >= nblk1){ wg -= nblk1; A = A2; Bt = Bt2; C = C2p; }
  const int xcd = wg & 7, q = wg >> 3;
  const int bx  = q & ((1 << lnx) - 1);
  const int by  = (xcd << 3) + (q >> lnx);
  const int row0 = by * 256, col0 = bx * 256;

  const int abase = (wm*128 + lr)*128;          // A region: [0, 32K)
  const int bbase = 32768 + (wn*64 + lr)*128;   // B region: [32K, 64K)

  floatx4 acc[8][4] = {};

  auto stageT = [&](int kt){
    #pragma unroll
    for (int h = 0; h < 2; ++h)
      #pragma unroll
      for (int call = 0; call < 2; ++call){
        const int L  = (call << 9) + tid;
        const int rl = L >> 3;
        const int cc = (L & 7) ^ (rl & 7);          // inverse-swizzled source
        gload16(A + (size_t)(row0 + h*128 + rl)*lda + kt*64 + cc*8,
                smem + h*16384 + L*16);
      }
    #pragma unroll
    for (int h = 0; h < 2; ++h)
      #pragma unroll
      for (int call = 0; call < 2; ++call){
        const int L  = (call << 9) + tid;
        const int rl = L >> 3;
        const int cc = (L & 7) ^ (rl & 7);
        gload16(Bt + (size_t)(col0 + h*128 + rl)*1024 + kt*64 + cc*8,
                smem + 32768 + h*16384 + L*16);
      }
  };

  stageT(0);

  short8 a0[8], a1[8], b0[4], b1[4];

  for (int t = 0; t < NT; ++t){
    asm volatile("s_waitcnt vmcnt(0)" ::: "memory");
    BARFENCE;                        // tile t fully in LDS
    LDAS(a0, 0); LDBS(b0, 0);        // 24 x ds_read_b128
    LDAS(a1, 1); LDBS(b1, 1);
    asm volatile("s_waitcnt lgkmcnt(0)" ::: "memory");
    BARFENCE;                        // all reads in registers -> safe to overwrite
    if (t+1 < NT) stageT(t+1);       // issue next tile; latency hides under MFMA
    __builtin_amdgcn_s_setprio(1);
    MM32(a0, b0);
    MM32(a1, b1);
    __builtin_amdgcn_s_setprio(0);
  }

  const int crow = row0 + wm*128;
  const int ccol = col0 + wn*64 + lr;
  #pragma unroll
  for (int m = 0; m < 8; ++m){
    #pragma unroll
    for (int j = 0; j < 4; ++j){
      unsigned short* cp = C + (size_t)(crow + m*16 + kg*4 + j)*ldc + ccol;
      #pragma unroll
      for (int n = 0; n < 4; ++n) cp[n*16] = f2bf(acc[m][n][j]);
    }
  }
}

// ---------------- epilogue 1 (wave-per-row, lane owns balls lane+64i) ----------------
__global__ __launch_bounds__(256) __attribute__((amdgpu_waves_per_eu(4,4)))
void epi1_k(unsigned short* C1, const unsigned short* C2, const unsigned short* hbf,
            unsigned short* rphb, const float* bz, const float* br,
            const float* h_nrm, const float* x_nrm, float* rph_nrm){
  const int lane = threadIdx.x & 63;
  const int row  = rowswz(blockIdx.x)*4 + (threadIdx.x >> 6);
  unsigned short* c1lo = C1 + (size_t)row*2048;
  unsigned short* c1hi = c1lo + 1024;
  const unsigned short* c2lo = C2 + (size_t)row*2048;
  const unsigned short* c2hi = c2lo + 1024;
  const unsigned short* hr = hbf + (size_t)row*1024;
  unsigned short* rr = rphb + (size_t)row*1024;

  float4 mzh[4], mrh[4], mzx[4], mrx[4];
  float s0 = 0.f, s1 = 0.f, s2 = 0.f, s3 = 0.f;
  #pragma unroll
  for (int i = 0; i < 4; ++i){
    const int b = lane + 64*i;
    mzh[i] = ld_ball(c1lo, b); mrh[i] = ld_ball(c1hi, b);
    mzx[i] = ld_ball(c2lo, b); mrx[i] = ld_ball(c2hi, b);
    s0 += dot4(mzh[i], mzh[i]); s1 += dot4(mzx[i], mzx[i]);
    s2 += dot4(mrh[i], mrh[i]); s3 += dot4(mrx[i], mrx[i]);
  }
  s0 = wsum(s0); s1 = wsum(s1); s2 = wsum(s2); s3 = wsum(s3);

  const float nMzh = fmaxf(fsqrt(s0), EPSF);
  const float nMzx = fmaxf(fsqrt(s1), EPSF);
  const float nMrh = fmaxf(fsqrt(s2), EPSF);
  const float nMrx = fmaxf(fsqrt(s3), EPSF);
  const float hnc = clipn(h_nrm[row]), xnc = clipn(x_nrm[row]);
  const float atH = fatanh(hnc), atX = fatanh(xnc);
  const float swz = __fdividef(ftanh_pos(__fdividef(nMzh, hnc)*atH), nMzh);
  const float suz = __fdividef(ftanh_pos(__fdividef(nMzx, xnc)*atX), nMzx);
  const float swr = __fdividef(ftanh_pos(__fdividef(nMrh, hnc)*atH), nMrh);
  const float sur = __fdividef(ftanh_pos(__fdividef(nMrx, xnc)*atX), nMrx);

  float sr = 0.f;
  #pragma unroll
  for (int i = 0; i < 4; ++i){
    const int b = lane + 64*i;
    const float4 bz4 = ((const float4*)bz)[b];
    const float4 br4 = ((const float4*)br)[b];
    const float4 z4  = logmap_sig4(mob_add4(mob_add4(scal4(mzh[i],swz), scal4(mzx[i],suz)), bz4));
    const float4 UxR = scal4(mrx[i], sur);
    const float4 r4  = logmap_sig4(mob_add4(mob_add4(scal4(mrh[i],swr), UxR), br4));
    st_ball(c1lo, b, z4);
    st_ball(c1hi, b, UxR);
    const float4 h4  = ld_ball(hr, b);
    const float4 rph = mob_pp4(h4, r4);
    st_ball(rr, b, rph);
    sr += dot4(rph, rph);
  }
  sr = wsum(sr);
  if (lane == 0) rph_nrm[row] = fsqrt(sr);
}

// ---------------- epilogue 2 (wave-per-row): h_tilde, final new_h ----------------
__global__ __launch_bounds__(256) __attribute__((amdgpu_waves_per_eu(4,4)))
void epi2_k(const unsigned short* C1, const unsigned short* C2,
            const unsigned short* hbf, const float* bh,
            const float* rph_nrm, float* out){
  const int lane = threadIdx.x & 63;
  const int row  = rowswz(blockIdx.x)*4 + (threadIdx.x >> 6);
  const unsigned short* c1lo = C1 + (size_t)row*2048;
  const unsigned short* c1hi = c1lo + 1024;
  const unsigned short* c2hi = C2 + (size_t)row*2048 + 1024;
  const unsigned short* hr = hbf + (size_t)row*1024;
  float4* outr = (float4*)(out + (size_t)row*1024);

  float4 mh[4];
  float ss = 0.f;
  #pragma unroll
  for (int i = 0; i < 4; ++i){
    mh[i] = ld_ball(c2hi, lane + 64*i);
    ss += dot4(mh[i], mh[i]);
  }
  ss = wsum(ss);
  const float nMh = fmaxf(fsqrt(ss), EPSF);
  const float rnc = clipn(rph_nrm[row]);
  const float swh = __fdividef(ftanh_pos(__fdividef(nMh, rnc)*fatanh(rnc)), nMh);

  #pragma unroll
  for (int i = 0; i < 4; ++i){
    const int b = lane + 64*i;
    const float4 WhH = scal4(mh[i], swh);
    const float4 Ux4 = ld_ball(c1hi, b);
    const float4 bh4 = ((const float4*)bh)[b];
    const float4 ht  = mob_add4(mob_add4(WhH, Ux4), bh4);
    const float4 h4  = ld_ball(hr, b);
    const float4 nh4 = make_float4(-h4.x, -h4.y, -h4.z, -h4.w);
    const float4 m4  = mob_add4(nh4, ht);
    const float4 z4  = ld_ball(c1lo, b);
    const float4 p4  = mob_pp4(m4, z4);
    outr[b] = mob_add4(h4, p4);
  }
}

extern "C" void kernel_launch(void* const* d_in, const int* in_sizes, int n_in,
                              void* d_out, int out_size, void* d_ws, size_t ws_size,
                              hipStream_t stream) {
  (void)in_sizes; (void)n_in; (void)out_size; (void)ws_size;
  const float* hyp_x  = (const float*)d_in[0];
  const float* hidden = (const float*)d_in[1];
  const float* w_z = (const float*)d_in[2];
  const float* w_r = (const float*)d_in[3];
  const float* w_h = (const float*)d_in[4];
  const float* u_z = (const float*)d_in[5];
  const float* u_r = (const float*)d_in[6];
  // d_in[7] = u_h unused by the reference (it uses u_r for h_tilde)
  const float* b_z = (const float*)d_in[8];
  const float* b_r = (const float*)d_in[9];
  const float* b_h = (const float*)d_in[10];
  float* out = (float*)d_out;

  const size_t NROW = 16384, MAT = NROW*1024;
  unsigned short* hbf = (unsigned short*)d_ws;   // bf16(hidden) — live to the end
  unsigned short* xbf = hbf + MAT;               // bf16(x) -> later rph (tight)
  unsigned short* C1  = xbf + MAT;               // [M][2048]: Mz_h|Mr_h -> z|Ux
  unsigned short* wzr = C1 + 2*MAT;              // [2048][1024]: wzt | wrt
  unsigned short* uzr = wzr + 2*1048576;
  unsigned short* wht = uzr + 2*1048576;
  float* h_n   = (float*)(wht + 1048576);
  float* x_n   = h_n + NROW;
  float* rph_n = x_n + NROW;
  unsigned short* C2 = (unsigned short*)d_out;   // [M][2048]: Mz_x|Mr_x -> (dead)|Mh -> fp32 out

  cast2_k<<<dim3(8192), dim3(256), 0, stream>>>(hidden, hyp_x, hbf, xbf, h_n, x_n);
  wcast5_k<<<dim3(32,32,5), dim3(32,8), 0, stream>>>(w_z, w_r, u_z, u_r, w_h,
                                                     wzr, uzr, wht);

  // merged dual-GEMM: blocks 0..511 -> h@wzr->C1 ; 512..1023 -> x@uzr->C2
  gemm1b_k<<<dim3(1024), dim3(512), 0, stream>>>(hbf, wzr, C1, xbf, uzr, C2,
                                                 1024, 2048, 3, 512);

  epi1_k<<<dim3(4096), dim3(256), 0, stream>>>(C1, C2, hbf, xbf /*rph out*/,
                                               b_z, b_r, h_n, x_n, rph_n);

  // Mh = rph @ Wh : A = xbf (lda=1024), C -> C2 hi half (over dead Mr_x)
  gemm1b_k<<<dim3(256), dim3(512), 0, stream>>>(xbf, wht, C2 + 1024,
                                                xbf, wht, C2 + 1024,
                                                1024, 2048, 2, 256);

  epi2_k<<<dim3(4096), dim3(256), 0, stream>>>(C1, C2, hbf, b_h, rph_n, out);
}

// Round 12
// 313.691 us; speedup vs baseline: 8.3684x; 8.3684x over previous
//
#include <hip/hip_runtime.h>
#include <stdint.h>

#define EPSF 1e-5f
#define MAXNF (1.0f - 1e-5f)

typedef __attribute__((ext_vector_type(8))) short short8;
typedef __attribute__((ext_vector_type(4))) float floatx4;

__device__ __forceinline__ unsigned short f2bf(float f){
  union { float f; uint32_t u; } v; v.f = f;
  return (unsigned short)((v.u + 0x7FFFu + ((v.u >> 16) & 1u)) >> 16);
}
__device__ __forceinline__ float bf_lo(uint32_t u){
  union { uint32_t u; float f; } v; v.u = u << 16; return v.f;
}
__device__ __forceinline__ float bf_hi(uint32_t u){
  union { uint32_t u; float f; } v; v.u = u & 0xffff0000u; return v.f;
}
__device__ __forceinline__ uint32_t cvtpk(float lo, float hi){
  uint32_t r; asm("v_cvt_pk_bf16_f32 %0, %1, %2" : "=v"(r) : "v"(lo), "v"(hi));
  return r;
}
__device__ __forceinline__ float fsqrt(float x){ return __builtin_amdgcn_sqrtf(x); }

__device__ __forceinline__ float4 ld_ball(const unsigned short* rowp, int b){
  const uint2 u = *(const uint2*)(rowp + 4*b);
  return make_float4(bf_lo(u.x), bf_hi(u.x), bf_lo(u.y), bf_hi(u.y));
}
__device__ __forceinline__ void st_ball(unsigned short* rowp, int b, float4 f){
  uint2 u; u.x = cvtpk(f.x, f.y); u.y = cvtpk(f.z, f.w);
  *(uint2*)(rowp + 4*b) = u;
}

__device__ __forceinline__ void gload16(const void* g, void* l){
  __builtin_amdgcn_global_load_lds(
      (__attribute__((address_space(1))) void*)(uintptr_t)g,
      (__attribute__((address_space(3))) void*)l, 16, 0, 0);
}

// ---- fast transcendentals (v_exp/v_log/v_rcp; ~1e-6 rel err vs 1.7e-3 tol) ----
__device__ __forceinline__ float fatanh(float x){
  return 0.5f * __logf(__fdividef(1.f + x, 1.f - x));
}
__device__ __forceinline__ float ftanh_pos(float x){
  const float t = __expf(-2.f * x);
  return __fdividef(1.f - t, 1.f + t);
}
__device__ __forceinline__ float fsig(float x){
  return __fdividef(1.f, 1.f + __expf(-x));
}

__device__ __forceinline__ float wsum(float v){
  #pragma unroll
  for (int o = 32; o; o >>= 1) v += __shfl_xor(v, o);
  return v;
}

// ---------------- per-ball Mobius helpers ----------------
__device__ __forceinline__ float dot4(const float4 a, const float4 b){
  return a.x*b.x + a.y*b.y + a.z*b.z + a.w*b.w;
}
__device__ __forceinline__ float4 scal4(const float4 a, float s){
  return make_float4(a.x*s, a.y*s, a.z*s, a.w*s);
}
__device__ __forceinline__ float clipn(float n){ return fminf(fmaxf(n, EPSF), MAXNF); }

__device__ __forceinline__ float4 mob_add4(const float4 u, const float4 v){
  const float uv = dot4(u,v), uu = dot4(u,u), vv = dot4(v,v);
  const float cu = 1.f + 2.f*uv + vv, cv = 1.f - uu;
  const float inv = __fdividef(1.f, fmaxf(1.f + 2.f*uv + uu*vv, EPSF));
  return make_float4((cu*u.x + cv*v.x)*inv, (cu*u.y + cv*v.y)*inv,
                     (cu*u.z + cv*v.z)*inv, (cu*u.w + cv*v.w)*inv);
}
__device__ __forceinline__ float4 logmap_sig4(const float4 y){
  const float nc = clipn(fsqrt(dot4(y,y)));
  const float s = __fdividef(fatanh(nc), nc);
  return make_float4(fsig(s*y.x), fsig(s*y.y), fsig(s*y.z), fsig(s*y.w));
}
__device__ __forceinline__ float4 mob_pp4(const float4 x, const float4 u){
  const float4 ux = make_float4(u.x*x.x, u.y*x.y, u.z*x.z, u.w*x.w);
  const float xn = clipn(fsqrt(dot4(x,x)));
  const float uxn = fmaxf(fsqrt(dot4(ux,ux)), EPSF);
  const float s = __fdividef(ftanh_pos(__fdividef(uxn, xn) * fatanh(xn)), uxn);
  return scal4(ux, s);
}

// XCD-chunk swizzle for 4096-block row kernels (producer/consumer L2 alignment)
__device__ __forceinline__ int rowswz(int b){ return ((b & 7) << 9) + (b >> 3); }

// ===== fused prep: bf16 casts + row norms (blocks 0..8191) AND the 5 weight
// ===== transpose-casts (blocks 8192..13311) in ONE dispatch =====
__global__ void prep_k(const float* __restrict__ H, const float* __restrict__ X,
                       unsigned short* __restrict__ Hbf, unsigned short* __restrict__ Xbf,
                       float* __restrict__ h_n, float* __restrict__ x_n,
                       const float* __restrict__ w_z, const float* __restrict__ w_r,
                       const float* __restrict__ u_z, const float* __restrict__ u_r,
                       const float* __restrict__ w_h,
                       unsigned short* __restrict__ wzr, unsigned short* __restrict__ uzr,
                       unsigned short* __restrict__ wht){
  __shared__ float tile[32][33];
  int blk = blockIdx.x;
  if (blk < 8192){
    const float* src; unsigned short* dst; float* nrm;
    if (blk < 4096){ src = H; dst = Hbf; nrm = h_n; }
    else { src = X; dst = Xbf; nrm = x_n; blk -= 4096; }
    blk = rowswz(blk);
    const int lane = threadIdx.x & 63;
    const int row  = blk*4 + (threadIdx.x >> 6);
    const float4* xr = (const float4*)(src + (size_t)row*1024);
    unsigned short* br_ = dst + (size_t)row*1024;
    float ss = 0.f;
    #pragma unroll
    for (int i = 0; i < 4; ++i){
      const int b = lane + 64*i;
      const float4 v = xr[b];
      st_ball(br_, b, v);
      ss += dot4(v, v);
    }
    ss = wsum(ss);
    if (lane == 0) nrm[row] = fsqrt(ss);
  } else {
    blk -= 8192;                        // 5120 blocks: m = blk/1024, 32x32 grid
    const int m = blk >> 10, rest = blk & 1023;
    const int kb = rest & 31, nb = rest >> 5;
    const float* W; unsigned short* Wt;
    switch (m){
      case 0: W = w_z; Wt = wzr;           break;
      case 1: W = w_r; Wt = wzr + 1048576; break;
      case 2: W = u_z; Wt = uzr;           break;
      case 3: W = u_r; Wt = uzr + 1048576; break;
      default: W = w_h; Wt = wht;          break;
    }
    const int tx = threadIdx.x & 31, ty = threadIdx.x >> 5;   // 32 x 8
    const int k0 = kb * 32, n0 = nb * 32;
    #pragma unroll
    for (int i = 0; i < 4; ++i)
      tile[ty + i*8][tx] = W[(size_t)(k0 + ty + i*8) * 1024 + n0 + tx];
    __syncthreads();
    #pragma unroll
    for (int i = 0; i < 4; ++i)
      Wt[(size_t)(n0 + ty + i*8) * 1024 + k0 + tx] = f2bf(tile[tx][ty + i*8]);
  }
}

// ====== 8-phase 256x256 bf16 MFMA GEMM (r8/r10 16x16x32 version — 0 conflicts) ======
#define NT 16

#define BARFENCE do { __builtin_amdgcn_s_barrier(); asm volatile("" ::: "memory"); } while(0)
#define LDA4(dst, MO, BUF) do { _Pragma("unroll") for (int m_=0;m_<4;++m_) \
  _Pragma("unroll") for (int k_=0;k_<2;++k_) \
    dst[m_][k_] = *(const short8*)(smem + (BUF)*32768 + abase + (MO+m_)*2048 + ((((k_<<2)+kg)^x7)<<4)); } while(0)
#define LDB2(dst, NO, BUF) do { _Pragma("unroll") for (int n_=0;n_<2;++n_) \
  _Pragma("unroll") for (int k_=0;k_<2;++k_) \
    dst[n_][k_] = *(const short8*)(smem + (BUF)*32768 + bbase + (NO+n_)*2048 + ((((k_<<2)+kg)^x7)<<4)); } while(0)
#define QUAD(AF, MO, BF, NO) do { _Pragma("unroll") for (int m_=0;m_<4;++m_) \
  _Pragma("unroll") for (int n_=0;n_<2;++n_) \
  _Pragma("unroll") for (int k_=0;k_<2;++k_) \
    acc[MO+m_][NO+n_] = __builtin_amdgcn_mfma_f32_16x16x32_bf16(AF[m_][k_], BF[n_][k_], acc[MO+m_][NO+n_], 0,0,0); } while(0)

__global__ __launch_bounds__(512, 2) void gemm8_k(const unsigned short* __restrict__ A,
                                                  const unsigned short* __restrict__ Bt,
                                                  unsigned short* __restrict__ C,
                                                  int lda, int ldc, int lnx){
  __shared__ unsigned char smem[131072];
  const int tid = threadIdx.x;
  const int lane = tid & 63, w = tid >> 6;
  const int wm = w >> 2, wn = w & 3;
  const int lr = lane & 15, kg = lane >> 4;
  const int x7 = lr & 7;

  const int wg  = blockIdx.x;
  const int xcd = wg & 7, q = wg >> 3;
  const int bx  = q & ((1 << lnx) - 1);
  const int by  = (xcd << 3) + (q >> lnx);
  const int row0 = by * 256, col0 = bx * 256;

  const int abase = (wm*128 + lr)*128;          // A region: [0, 64K)
  const int bbase = 65536 + (wn*64 + lr)*128;   // B region: [64K, 128K)

  floatx4 acc[8][4] = {};

  auto stageH = [&](int regionByte, const unsigned short* src, int srow0, int ld, int kt){
    #pragma unroll
    for (int call = 0; call < 2; ++call){
      const int L  = (call << 9) + tid;
      const int rl = L >> 3;
      const int cc = (L & 7) ^ (rl & 7);            // inverse-swizzled source
      gload16(src + (size_t)(srow0 + rl)*ld + kt*64 + cc*8,
              smem + regionByte + L*16);            // linear LDS dest
    }
  };
  auto stageA = [&](int kt, int h){ stageH((kt&1)*32768 + h*16384, A, row0 + h*128, lda, kt); };
  auto stageB = [&](int kt, int h){ stageH(65536 + (kt&1)*32768 + h*16384, Bt, col0 + h*128, 1024, kt); };

  // prologue: tiles 0 and 1 fully staged
  stageA(0,0); stageA(0,1); stageB(0,0); stageB(0,1);
  stageA(1,0); stageA(1,1); stageB(1,0); stageB(1,1);
  asm volatile("s_waitcnt vmcnt(8)" ::: "memory");
  BARFENCE;

  short8 aL[4][2], aH[4][2], bA[2][2], bB[2][2];
  LDA4(aL, 0, 0);
  LDB2(bA, 0, 0);

  for (int t = 0; t < NT; ++t){
    const int bufb = t & 1;
    // ---- ph1: read bB(t); MFMA aL·bA
    LDB2(bB, 2, bufb);
    BARFENCE;
    __builtin_amdgcn_s_setprio(1); QUAD(aL, 0, bA, 0); __builtin_amdgcn_s_setprio(0);
    BARFENCE;
    // ---- ph2: read aH(t); MFMA aL·bB
    LDA4(aH, 4, bufb);
    BARFENCE;
    __builtin_amdgcn_s_setprio(1); QUAD(aL, 0, bB, 2); __builtin_amdgcn_s_setprio(0);
    BARFENCE;
    // ---- ph3: stage B(t+2); counted vmcnt; MFMA aH·bB; read-ahead aL(t+1)
    if (t+2 < NT){
      stageB(t+2,0); stageB(t+2,1);
      asm volatile("s_waitcnt vmcnt(4)" ::: "memory");
    } else if (t+1 < NT){
      asm volatile("s_waitcnt vmcnt(0)" ::: "memory");
    }
    BARFENCE;
    __builtin_amdgcn_s_setprio(1); QUAD(aH, 4, bB, 2); __builtin_amdgcn_s_setprio(0);
    if (t+1 < NT) LDA4(aL, 0, bufb^1);
    BARFENCE;
    // ---- ph4: stage A(t+2); MFMA aH·bA; read-ahead bA(t+1)
    if (t+2 < NT){ stageA(t+2,0); stageA(t+2,1); }
    BARFENCE;
    __builtin_amdgcn_s_setprio(1); QUAD(aH, 4, bA, 0); __builtin_amdgcn_s_setprio(0);
    if (t+1 < NT) LDB2(bA, 0, bufb^1);
    BARFENCE;
  }

  const int crow = row0 + wm*128;
  const int ccol = col0 + wn*64 + lr;
  #pragma unroll
  for (int m = 0; m < 8; ++m){
    #pragma unroll
    for (int j = 0; j < 4; ++j){
      unsigned short* cp = C + (size_t)(crow + m*16 + kg*4 + j)*ldc + ccol;
      #pragma unroll
      for (int n = 0; n < 4; ++n) cp[n*16] = f2bf(acc[m][n][j]);
    }
  }
}

// ---------------- epilogue 1 (wave-per-row, lane owns balls lane+64i) ----------------
// C1 = [M][2048]: Mz_h|Mr_h -> z|Ux ;  C2 = [M][2048] (d_out): Mz_x|Mr_x (dead after)
// rph goes to rphb = xbf (tight [M][1024]) so the Wh GEMM gets lda=1024.
__global__ __launch_bounds__(256) __attribute__((amdgpu_waves_per_eu(4,4)))
void epi1_k(unsigned short* C1, const unsigned short* C2, const unsigned short* hbf,
            unsigned short* rphb, const float* bz, const float* br,
            const float* h_nrm, const float* x_nrm, float* rph_nrm){
  const int lane = threadIdx.x & 63;
  const int row  = rowswz(blockIdx.x)*4 + (threadIdx.x >> 6);
  unsigned short* c1lo = C1 + (size_t)row*2048;
  unsigned short* c1hi = c1lo + 1024;
  const unsigned short* c2lo = C2 + (size_t)row*2048;
  const unsigned short* c2hi = c2lo + 1024;
  const unsigned short* hr = hbf + (size_t)row*1024;
  unsigned short* rr = rphb + (size_t)row*1024;

  float4 mzh[4], mrh[4], mzx[4], mrx[4];
  float s0 = 0.f, s1 = 0.f, s2 = 0.f, s3 = 0.f;
  #pragma unroll
  for (int i = 0; i < 4; ++i){
    const int b = lane + 64*i;
    mzh[i] = ld_ball(c1lo, b); mrh[i] = ld_ball(c1hi, b);
    mzx[i] = ld_ball(c2lo, b); mrx[i] = ld_ball(c2hi, b);
    s0 += dot4(mzh[i], mzh[i]); s1 += dot4(mzx[i], mzx[i]);
    s2 += dot4(mrh[i], mrh[i]); s3 += dot4(mrx[i], mrx[i]);
  }
  s0 = wsum(s0); s1 = wsum(s1); s2 = wsum(s2); s3 = wsum(s3);

  const float nMzh = fmaxf(fsqrt(s0), EPSF);
  const float nMzx = fmaxf(fsqrt(s1), EPSF);
  const float nMrh = fmaxf(fsqrt(s2), EPSF);
  const float nMrx = fmaxf(fsqrt(s3), EPSF);
  const float hnc = clipn(h_nrm[row]), xnc = clipn(x_nrm[row]);
  const float atH = fatanh(hnc), atX = fatanh(xnc);
  const float swz = __fdividef(ftanh_pos(__fdividef(nMzh, hnc)*atH), nMzh);
  const float suz = __fdividef(ftanh_pos(__fdividef(nMzx, xnc)*atX), nMzx);
  const float swr = __fdividef(ftanh_pos(__fdividef(nMrh, hnc)*atH), nMrh);
  const float sur = __fdividef(ftanh_pos(__fdividef(nMrx, xnc)*atX), nMrx);

  float sr = 0.f;
  #pragma unroll
  for (int i = 0; i < 4; ++i){
    const int b = lane + 64*i;
    const float4 bz4 = ((const float4*)bz)[b];
    const float4 br4 = ((const float4*)br)[b];
    const float4 z4  = logmap_sig4(mob_add4(mob_add4(scal4(mzh[i],swz), scal4(mzx[i],suz)), bz4));
    const float4 UxR = scal4(mrx[i], sur);
    const float4 r4  = logmap_sig4(mob_add4(mob_add4(scal4(mrh[i],swr), UxR), br4));
    st_ball(c1lo, b, z4);
    st_ball(c1hi, b, UxR);
    const float4 h4  = ld_ball(hr, b);
    const float4 rph = mob_pp4(h4, r4);
    st_ball(rr, b, rph);                 // tight rph buffer (over dead xbf)
    sr += dot4(rph, rph);
  }
  sr = wsum(sr);
  if (lane == 0) rph_nrm[row] = fsqrt(sr);
}

// ---------------- epilogue 2 (wave-per-row): h_tilde, final new_h ----------------
__global__ __launch_bounds__(256) __attribute__((amdgpu_waves_per_eu(4,4)))
void epi2_k(const unsigned short* C1, const unsigned short* C2,
            const unsigned short* hbf, const float* bh,
            const float* rph_nrm, float* out){
  const int lane = threadIdx.x & 63;
  const int row  = rowswz(blockIdx.x)*4 + (threadIdx.x >> 6);
  const unsigned short* c1lo = C1 + (size_t)row*2048;
  const unsigned short* c1hi = c1lo + 1024;
  const unsigned short* c2hi = C2 + (size_t)row*2048 + 1024;
  const unsigned short* hr = hbf + (size_t)row*1024;
  float4* outr = (float4*)(out + (size_t)row*1024);

  float4 mh[4];
  float ss = 0.f;
  #pragma unroll
  for (int i = 0; i < 4; ++i){
    mh[i] = ld_ball(c2hi, lane + 64*i);
    ss += dot4(mh[i], mh[i]);
  }
  ss = wsum(ss);
  const float nMh = fmaxf(fsqrt(ss), EPSF);
  const float rnc = clipn(rph_nrm[row]);
  const float swh = __fdividef(ftanh_pos(__fdividef(nMh, rnc)*fatanh(rnc)), nMh);

  #pragma unroll
  for (int i = 0; i < 4; ++i){
    const int b = lane + 64*i;
    const float4 WhH = scal4(mh[i], swh);
    const float4 Ux4 = ld_ball(c1hi, b);
    const float4 bh4 = ((const float4*)bh)[b];
    const float4 ht  = mob_add4(mob_add4(WhH, Ux4), bh4);
    const float4 h4  = ld_ball(hr, b);
    const float4 nh4 = make_float4(-h4.x, -h4.y, -h4.z, -h4.w);
    const float4 m4  = mob_add4(nh4, ht);
    const float4 z4  = ld_ball(c1lo, b);
    const float4 p4  = mob_pp4(m4, z4);
    outr[b] = mob_add4(h4, p4);
  }
}

extern "C" void kernel_launch(void* const* d_in, const int* in_sizes, int n_in,
                              void* d_out, int out_size, void* d_ws, size_t ws_size,
                              hipStream_t stream) {
  (void)in_sizes; (void)n_in; (void)out_size; (void)ws_size;
  const float* hyp_x  = (const float*)d_in[0];
  const float* hidden = (const float*)d_in[1];
  const float* w_z = (const float*)d_in[2];
  const float* w_r = (const float*)d_in[3];
  const float* w_h = (const float*)d_in[4];
  const float* u_z = (const float*)d_in[5];
  const float* u_r = (const float*)d_in[6];
  // d_in[7] = u_h unused by the reference (it uses u_r for h_tilde)
  const float* b_z = (const float*)d_in[8];
  const float* b_r = (const float*)d_in[9];
  const float* b_h = (const float*)d_in[10];
  float* out = (float*)d_out;

  const size_t NROW = 16384, MAT = NROW*1024;
  unsigned short* hbf = (unsigned short*)d_ws;   // bf16(hidden) — live to the end
  unsigned short* xbf = hbf + MAT;               // bf16(x) -> later rph (tight, lda=1024)
  unsigned short* C1  = xbf + MAT;               // [M][2048]: Mz_h|Mr_h -> z|Ux
  unsigned short* wzr = C1 + 2*MAT;              // [2048][1024]: wzt | wrt
  unsigned short* uzr = wzr + 2*1048576;
  unsigned short* wht = uzr + 2*1048576;
  float* h_n   = (float*)(wht + 1048576);
  float* x_n   = h_n + NROW;
  float* rph_n = x_n + NROW;
  unsigned short* C2 = (unsigned short*)d_out;   // [M][2048]: Mz_x|Mr_x -> (dead)|Mh -> fp32 out

  // fused prep: casts+norms (8192 blocks) + 5 weight transposes (5120 blocks)
  prep_k<<<dim3(13312), dim3(256), 0, stream>>>(hidden, hyp_x, hbf, xbf, h_n, x_n,
                                                w_z, w_r, u_z, u_r, w_h,
                                                wzr, uzr, wht);

  // 64 row-panels x 8 col-panels = 512 blocks (lnx=3); Wh: x4 cols = 256 (lnx=2)
  gemm8_k<<<dim3(512), dim3(512), 0, stream>>>(hbf, wzr, C1, 1024, 2048, 3); // Mz_h|Mr_h
  gemm8_k<<<dim3(512), dim3(512), 0, stream>>>(xbf, uzr, C2, 1024, 2048, 3); // Mz_x|Mr_x

  epi1_k<<<dim3(4096), dim3(256), 0, stream>>>(C1, C2, hbf, xbf /*rph out*/,
                                               b_z, b_r, h_n, x_n, rph_n);

  // Mh = rph @ Wh : A = xbf (tight lda=1024), C -> C2 hi half (over dead Mr_x)
  gemm8_k<<<dim3(256), dim3(512), 0, stream>>>(xbf, wht, C2 + 1024, 1024, 2048, 2);

  epi2_k<<<dim3(4096), dim3(256), 0, stream>>>(C1, C2, hbf, b_h, rph_n, out);
}

// Round 13
// 308.131 us; speedup vs baseline: 8.5194x; 1.0180x over previous
//
#include <hip/hip_runtime.h>
#include <stdint.h>

#define EPSF 1e-5f
#define MAXNF (1.0f - 1e-5f)

typedef __attribute__((ext_vector_type(8))) short short8;
typedef __attribute__((ext_vector_type(4))) float floatx4;

__device__ __forceinline__ unsigned short f2bf(float f){
  union { float f; uint32_t u; } v; v.f = f;
  return (unsigned short)((v.u + 0x7FFFu + ((v.u >> 16) & 1u)) >> 16);
}
__device__ __forceinline__ float bf_lo(uint32_t u){
  union { uint32_t u; float f; } v; v.u = u << 16; return v.f;
}
__device__ __forceinline__ float bf_hi(uint32_t u){
  union { uint32_t u; float f; } v; v.u = u & 0xffff0000u; return v.f;
}
__device__ __forceinline__ uint32_t cvtpk(float lo, float hi){
  uint32_t r; asm("v_cvt_pk_bf16_f32 %0, %1, %2" : "=v"(r) : "v"(lo), "v"(hi));
  return r;
}
__device__ __forceinline__ float fsqrt(float x){ return __builtin_amdgcn_sqrtf(x); }

__device__ __forceinline__ float4 ld_ball(const unsigned short* rowp, int b){
  const uint2 u = *(const uint2*)(rowp + 4*b);
  return make_float4(bf_lo(u.x), bf_hi(u.x), bf_lo(u.y), bf_hi(u.y));
}
__device__ __forceinline__ void st_ball(unsigned short* rowp, int b, float4 f){
  uint2 u; u.x = cvtpk(f.x, f.y); u.y = cvtpk(f.z, f.w);
  *(uint2*)(rowp + 4*b) = u;
}

__device__ __forceinline__ void gload16(const void* g, void* l){
  __builtin_amdgcn_global_load_lds(
      (__attribute__((address_space(1))) void*)(uintptr_t)g,
      (__attribute__((address_space(3))) void*)l, 16, 0, 0);
}

// ---- fast transcendentals (v_exp/v_log/v_rcp; ~1e-6 rel err vs 1.7e-3 tol) ----
__device__ __forceinline__ float fatanh(float x){
  return 0.5f * __logf(__fdividef(1.f + x, 1.f - x));
}
__device__ __forceinline__ float ftanh_pos(float x){
  const float t = __expf(-2.f * x);
  return __fdividef(1.f - t, 1.f + t);
}
__device__ __forceinline__ float fsig(float x){
  return __fdividef(1.f, 1.f + __expf(-x));
}

__device__ __forceinline__ float wsum(float v){
  #pragma unroll
  for (int o = 32; o; o >>= 1) v += __shfl_xor(v, o);
  return v;
}

// ---------------- per-ball Mobius helpers ----------------
__device__ __forceinline__ float dot4(const float4 a, const float4 b){
  return a.x*b.x + a.y*b.y + a.z*b.z + a.w*b.w;
}
__device__ __forceinline__ float4 scal4(const float4 a, float s){
  return make_float4(a.x*s, a.y*s, a.z*s, a.w*s);
}
__device__ __forceinline__ float clipn(float n){ return fminf(fmaxf(n, EPSF), MAXNF); }

__device__ __forceinline__ float4 mob_add4(const float4 u, const float4 v){
  const float uv = dot4(u,v), uu = dot4(u,u), vv = dot4(v,v);
  const float cu = 1.f + 2.f*uv + vv, cv = 1.f - uu;
  const float inv = __fdividef(1.f, fmaxf(1.f + 2.f*uv + uu*vv, EPSF));
  return make_float4((cu*u.x + cv*v.x)*inv, (cu*u.y + cv*v.y)*inv,
                     (cu*u.z + cv*v.z)*inv, (cu*u.w + cv*v.w)*inv);
}
__device__ __forceinline__ float4 logmap_sig4(const float4 y){
  const float nc = clipn(fsqrt(dot4(y,y)));
  const float s = __fdividef(fatanh(nc), nc);
  return make_float4(fsig(s*y.x), fsig(s*y.y), fsig(s*y.z), fsig(s*y.w));
}
__device__ __forceinline__ float4 mob_pp4(const float4 x, const float4 u){
  const float4 ux = make_float4(u.x*x.x, u.y*x.y, u.z*x.z, u.w*x.w);
  const float xn = clipn(fsqrt(dot4(x,x)));
  const float uxn = fmaxf(fsqrt(dot4(ux,ux)), EPSF);
  const float s = __fdividef(ftanh_pos(__fdividef(uxn, xn) * fatanh(xn)), uxn);
  return scal4(ux, s);
}

// XCD-chunk swizzle for 4096-block row kernels (producer/consumer L2 alignment)
__device__ __forceinline__ int rowswz(int b){ return ((b & 7) << 9) + (b >> 3); }

// ===== fused prep: bf16 casts + row norms (blocks 0..8191) AND the 5 weight
// ===== transpose-casts (blocks 8192..13311) in ONE dispatch =====
__global__ void prep_k(const float* __restrict__ H, const float* __restrict__ X,
                       unsigned short* __restrict__ Hbf, unsigned short* __restrict__ Xbf,
                       float* __restrict__ h_n, float* __restrict__ x_n,
                       const float* __restrict__ w_z, const float* __restrict__ w_r,
                       const float* __restrict__ u_z, const float* __restrict__ u_r,
                       const float* __restrict__ w_h,
                       unsigned short* __restrict__ wzr, unsigned short* __restrict__ uzr,
                       unsigned short* __restrict__ wht){
  __shared__ float tile[32][33];
  int blk = blockIdx.x;
  if (blk < 8192){
    const float* src; unsigned short* dst; float* nrm;
    if (blk < 4096){ src = H; dst = Hbf; nrm = h_n; }
    else { src = X; dst = Xbf; nrm = x_n; blk -= 4096; }
    blk = rowswz(blk);
    const int lane = threadIdx.x & 63;
    const int row  = blk*4 + (threadIdx.x >> 6);
    const float4* xr = (const float4*)(src + (size_t)row*1024);
    unsigned short* br_ = dst + (size_t)row*1024;
    float ss = 0.f;
    #pragma unroll
    for (int i = 0; i < 4; ++i){
      const int b = lane + 64*i;
      const float4 v = xr[b];
      st_ball(br_, b, v);
      ss += dot4(v, v);
    }
    ss = wsum(ss);
    if (lane == 0) nrm[row] = fsqrt(ss);
  } else {
    blk -= 8192;                        // 5120 blocks: m = blk/1024, 32x32 grid
    const int m = blk >> 10, rest = blk & 1023;
    const int kb = rest & 31, nb = rest >> 5;
    const float* W; unsigned short* Wt;
    switch (m){
      case 0: W = w_z; Wt = wzr;           break;
      case 1: W = w_r; Wt = wzr + 1048576; break;
      case 2: W = u_z; Wt = uzr;           break;
      case 3: W = u_r; Wt = uzr + 1048576; break;
      default: W = w_h; Wt = wht;          break;
    }
    const int tx = threadIdx.x & 31, ty = threadIdx.x >> 5;   // 32 x 8
    const int k0 = kb * 32, n0 = nb * 32;
    #pragma unroll
    for (int i = 0; i < 4; ++i)
      tile[ty + i*8][tx] = W[(size_t)(k0 + ty + i*8) * 1024 + n0 + tx];
    __syncthreads();
    #pragma unroll
    for (int i = 0; i < 4; ++i)
      Wt[(size_t)(n0 + ty + i*8) * 1024 + k0 + tx] = f2bf(tile[tx][ty + i*8]);
  }
}

// ====== 8-phase 256x256 bf16 MFMA GEMM (16x16x32, 0 conflicts) ======
// Dual-problem dispatch: blocks >= nblk1 run problem 2 (A2,Bt2,Cp2) — removes
// the inter-dispatch tail drain + launch boundary between the two big GEMMs.
#define NT 16

#define BARFENCE do { __builtin_amdgcn_s_barrier(); asm volatile("" ::: "memory"); } while(0)
#define LDA4(dst, MO, BUF) do { _Pragma("unroll") for (int m_=0;m_<4;++m_) \
  _Pragma("unroll") for (int k_=0;k_<2;++k_) \
    dst[m_][k_] = *(const short8*)(smem + (BUF)*32768 + abase + (MO+m_)*2048 + ((((k_<<2)+kg)^x7)<<4)); } while(0)
#define LDB2(dst, NO, BUF) do { _Pragma("unroll") for (int n_=0;n_<2;++n_) \
  _Pragma("unroll") for (int k_=0;k_<2;++k_) \
    dst[n_][k_] = *(const short8*)(smem + (BUF)*32768 + bbase + (NO+n_)*2048 + ((((k_<<2)+kg)^x7)<<4)); } while(0)
#define QUAD(AF, MO, BF, NO) do { _Pragma("unroll") for (int m_=0;m_<4;++m_) \
  _Pragma("unroll") for (int n_=0;n_<2;++n_) \
  _Pragma("unroll") for (int k_=0;k_<2;++k_) \
    acc[MO+m_][NO+n_] = __builtin_amdgcn_mfma_f32_16x16x32_bf16(AF[m_][k_], BF[n_][k_], acc[MO+m_][NO+n_], 0,0,0); } while(0)

__global__ __launch_bounds__(512, 2) void gemm8_k(const unsigned short* A,
                                                  const unsigned short* Bt,
                                                  unsigned short* C,
                                                  const unsigned short* A2,
                                                  const unsigned short* Bt2,
                                                  unsigned short* Cp2,
                                                  int lda, int ldc, int lnx, int nblk1){
  __shared__ unsigned char smem[131072];
  const int tid = threadIdx.x;
  const int lane = tid & 63, w = tid >> 6;
  const int wm = w >> 2, wn = w & 3;
  const int lr = lane & 15, kg = lane >> 4;
  const int x7 = lr & 7;

  int wg = blockIdx.x;
  if (wg >= nblk1){ wg -= nblk1; A = A2; Bt = Bt2; C = Cp2; }
  const int xcd = wg & 7, q = wg >> 3;
  const int bx  = q & ((1 << lnx) - 1);
  const int by  = (xcd << 3) + (q >> lnx);
  const int row0 = by * 256, col0 = bx * 256;

  const int abase = (wm*128 + lr)*128;          // A region: [0, 64K)
  const int bbase = 65536 + (wn*64 + lr)*128;   // B region: [64K, 128K)

  floatx4 acc[8][4] = {};

  auto stageH = [&](int regionByte, const unsigned short* src, int srow0, int ld, int kt){
    #pragma unroll
    for (int call = 0; call < 2; ++call){
      const int L  = (call << 9) + tid;
      const int rl = L >> 3;
      const int cc = (L & 7) ^ (rl & 7);            // inverse-swizzled source
      gload16(src + (size_t)(srow0 + rl)*ld + kt*64 + cc*8,
              smem + regionByte + L*16);            // linear LDS dest
    }
  };
  auto stageA = [&](int kt, int h){ stageH((kt&1)*32768 + h*16384, A, row0 + h*128, lda, kt); };
  auto stageB = [&](int kt, int h){ stageH(65536 + (kt&1)*32768 + h*16384, Bt, col0 + h*128, 1024, kt); };

  // prologue: tiles 0 and 1 fully staged
  stageA(0,0); stageA(0,1); stageB(0,0); stageB(0,1);
  stageA(1,0); stageA(1,1); stageB(1,0); stageB(1,1);
  asm volatile("s_waitcnt vmcnt(8)" ::: "memory");
  BARFENCE;

  short8 aL[4][2], aH[4][2], bA[2][2], bB[2][2];
  LDA4(aL, 0, 0);
  LDB2(bA, 0, 0);

  for (int t = 0; t < NT; ++t){
    const int bufb = t & 1;
    // ---- ph1: read bB(t); MFMA aL·bA
    LDB2(bB, 2, bufb);
    BARFENCE;
    __builtin_amdgcn_s_setprio(1); QUAD(aL, 0, bA, 0); __builtin_amdgcn_s_setprio(0);
    BARFENCE;
    // ---- ph2: read aH(t); MFMA aL·bB
    LDA4(aH, 4, bufb);
    BARFENCE;
    __builtin_amdgcn_s_setprio(1); QUAD(aL, 0, bB, 2); __builtin_amdgcn_s_setprio(0);
    BARFENCE;
    // ---- ph3: stage B(t+2); counted vmcnt; MFMA aH·bB; read-ahead aL(t+1)
    if (t+2 < NT){
      stageB(t+2,0); stageB(t+2,1);
      asm volatile("s_waitcnt vmcnt(4)" ::: "memory");
    } else if (t+1 < NT){
      asm volatile("s_waitcnt vmcnt(0)" ::: "memory");
    }
    BARFENCE;
    __builtin_amdgcn_s_setprio(1); QUAD(aH, 4, bB, 2); __builtin_amdgcn_s_setprio(0);
    if (t+1 < NT) LDA4(aL, 0, bufb^1);
    BARFENCE;
    // ---- ph4: stage A(t+2); MFMA aH·bA; read-ahead bA(t+1)
    if (t+2 < NT){ stageA(t+2,0); stageA(t+2,1); }
    BARFENCE;
    __builtin_amdgcn_s_setprio(1); QUAD(aH, 4, bA, 0); __builtin_amdgcn_s_setprio(0);
    if (t+1 < NT) LDB2(bA, 0, bufb^1);
    BARFENCE;
  }

  const int crow = row0 + wm*128;
  const int ccol = col0 + wn*64 + lr;
  #pragma unroll
  for (int m = 0; m < 8; ++m){
    #pragma unroll
    for (int j = 0; j < 4; ++j){
      unsigned short* cp = C + (size_t)(crow + m*16 + kg*4 + j)*ldc + ccol;
      #pragma unroll
      for (int n = 0; n < 4; ++n) cp[n*16] = f2bf(acc[m][n][j]);
    }
  }
}

// ---------------- epilogue 1 (wave-per-row, lane owns balls lane+64i) ----------------
// C1 = [M][2048]: Mz_h|Mr_h -> z|Ux ;  C2 = [M][2048] (d_out): Mz_x|Mr_x (dead after)
// rph goes to rphb = xbf (tight [M][1024]) so the Wh GEMM gets lda=1024.
__global__ __launch_bounds__(256) __attribute__((amdgpu_waves_per_eu(4,4)))
void epi1_k(unsigned short* C1, const unsigned short* C2, const unsigned short* hbf,
            unsigned short* rphb, const float* bz, const float* br,
            const float* h_nrm, const float* x_nrm, float* rph_nrm){
  const int lane = threadIdx.x & 63;
  const int row  = rowswz(blockIdx.x)*4 + (threadIdx.x >> 6);
  unsigned short* c1lo = C1 + (size_t)row*2048;
  unsigned short* c1hi = c1lo + 1024;
  const unsigned short* c2lo = C2 + (size_t)row*2048;
  const unsigned short* c2hi = c2lo + 1024;
  const unsigned short* hr = hbf + (size_t)row*1024;
  unsigned short* rr = rphb + (size_t)row*1024;

  float4 mzh[4], mrh[4], mzx[4], mrx[4];
  float s0 = 0.f, s1 = 0.f, s2 = 0.f, s3 = 0.f;
  #pragma unroll
  for (int i = 0; i < 4; ++i){
    const int b = lane + 64*i;
    mzh[i] = ld_ball(c1lo, b); mrh[i] = ld_ball(c1hi, b);
    mzx[i] = ld_ball(c2lo, b); mrx[i] = ld_ball(c2hi, b);
    s0 += dot4(mzh[i], mzh[i]); s1 += dot4(mzx[i], mzx[i]);
    s2 += dot4(mrh[i], mrh[i]); s3 += dot4(mrx[i], mrx[i]);
  }
  s0 = wsum(s0); s1 = wsum(s1); s2 = wsum(s2); s3 = wsum(s3);

  const float nMzh = fmaxf(fsqrt(s0), EPSF);
  const float nMzx = fmaxf(fsqrt(s1), EPSF);
  const float nMrh = fmaxf(fsqrt(s2), EPSF);
  const float nMrx = fmaxf(fsqrt(s3), EPSF);
  const float hnc = clipn(h_nrm[row]), xnc = clipn(x_nrm[row]);
  const float atH = fatanh(hnc), atX = fatanh(xnc);
  const float swz = __fdividef(ftanh_pos(__fdividef(nMzh, hnc)*atH), nMzh);
  const float suz = __fdividef(ftanh_pos(__fdividef(nMzx, xnc)*atX), nMzx);
  const float swr = __fdividef(ftanh_pos(__fdividef(nMrh, hnc)*atH), nMrh);
  const float sur = __fdividef(ftanh_pos(__fdividef(nMrx, xnc)*atX), nMrx);

  float sr = 0.f;
  #pragma unroll
  for (int i = 0; i < 4; ++i){
    const int b = lane + 64*i;
    const float4 bz4 = ((const float4*)bz)[b];
    const float4 br4 = ((const float4*)br)[b];
    const float4 z4  = logmap_sig4(mob_add4(mob_add4(scal4(mzh[i],swz), scal4(mzx[i],suz)), bz4));
    const float4 UxR = scal4(mrx[i], sur);
    const float4 r4  = logmap_sig4(mob_add4(mob_add4(scal4(mrh[i],swr), UxR), br4));
    st_ball(c1lo, b, z4);
    st_ball(c1hi, b, UxR);
    const float4 h4  = ld_ball(hr, b);
    const float4 rph = mob_pp4(h4, r4);
    st_ball(rr, b, rph);                 // tight rph buffer (over dead xbf)
    sr += dot4(rph, rph);
  }
  sr = wsum(sr);
  if (lane == 0) rph_nrm[row] = fsqrt(sr);
}

// ---------------- epilogue 2 (wave-per-row): h_tilde, final new_h ----------------
__global__ __launch_bounds__(256) __attribute__((amdgpu_waves_per_eu(4,4)))
void epi2_k(const unsigned short* C1, const unsigned short* C2,
            const unsigned short* hbf, const float* bh,
            const float* rph_nrm, float* out){
  const int lane = threadIdx.x & 63;
  const int row  = rowswz(blockIdx.x)*4 + (threadIdx.x >> 6);
  const unsigned short* c1lo = C1 + (size_t)row*2048;
  const unsigned short* c1hi = c1lo + 1024;
  const unsigned short* c2hi = C2 + (size_t)row*2048 + 1024;
  const unsigned short* hr = hbf + (size_t)row*1024;
  float4* outr = (float4*)(out + (size_t)row*1024);

  float4 mh[4];
  float ss = 0.f;
  #pragma unroll
  for (int i = 0; i < 4; ++i){
    mh[i] = ld_ball(c2hi, lane + 64*i);
    ss += dot4(mh[i], mh[i]);
  }
  ss = wsum(ss);
  const float nMh = fmaxf(fsqrt(ss), EPSF);
  const float rnc = clipn(rph_nrm[row]);
  const float swh = __fdividef(ftanh_pos(__fdividef(nMh, rnc)*fatanh(rnc)), nMh);

  #pragma unroll
  for (int i = 0; i < 4; ++i){
    const int b = lane + 64*i;
    const float4 WhH = scal4(mh[i], swh);
    const float4 Ux4 = ld_ball(c1hi, b);
    const float4 bh4 = ((const float4*)bh)[b];
    const float4 ht  = mob_add4(mob_add4(WhH, Ux4), bh4);
    const float4 h4  = ld_ball(hr, b);
    const float4 nh4 = make_float4(-h4.x, -h4.y, -h4.z, -h4.w);
    const float4 m4  = mob_add4(nh4, ht);
    const float4 z4  = ld_ball(c1lo, b);
    const float4 p4  = mob_pp4(m4, z4);
    outr[b] = mob_add4(h4, p4);
  }
}

extern "C" void kernel_launch(void* const* d_in, const int* in_sizes, int n_in,
                              void* d_out, int out_size, void* d_ws, size_t ws_size,
                              hipStream_t stream) {
  (void)in_sizes; (void)n_in; (void)out_size; (void)ws_size;
  const float* hyp_x  = (const float*)d_in[0];
  const float* hidden = (const float*)d_in[1];
  const float* w_z = (const float*)d_in[2];
  const float* w_r = (const float*)d_in[3];
  const float* w_h = (const float*)d_in[4];
  const float* u_z = (const float*)d_in[5];
  const float* u_r = (const float*)d_in[6];
  // d_in[7] = u_h unused by the reference (it uses u_r for h_tilde)
  const float* b_z = (const float*)d_in[8];
  const float* b_r = (const float*)d_in[9];
  const float* b_h = (const float*)d_in[10];
  float* out = (float*)d_out;

  const size_t NROW = 16384, MAT = NROW*1024;
  unsigned short* hbf = (unsigned short*)d_ws;   // bf16(hidden) — live to the end
  unsigned short* xbf = hbf + MAT;               // bf16(x) -> later rph (tight, lda=1024)
  unsigned short* C1  = xbf + MAT;               // [M][2048]: Mz_h|Mr_h -> z|Ux
  unsigned short* wzr = C1 + 2*MAT;              // [2048][1024]: wzt | wrt
  unsigned short* uzr = wzr + 2*1048576;
  unsigned short* wht = uzr + 2*1048576;
  float* h_n   = (float*)(wht + 1048576);
  float* x_n   = h_n + NROW;
  float* rph_n = x_n + NROW;
  unsigned short* C2 = (unsigned short*)d_out;   // [M][2048]: Mz_x|Mr_x -> (dead)|Mh -> fp32 out

  // fused prep: casts+norms (8192 blocks) + 5 weight transposes (5120 blocks)
  prep_k<<<dim3(13312), dim3(256), 0, stream>>>(hidden, hyp_x, hbf, xbf, h_n, x_n,
                                                w_z, w_r, u_z, u_r, w_h,
                                                wzr, uzr, wht);

  // merged dual-GEMM: blocks 0..511 h@[Wz|Wr]->C1, blocks 512..1023 x@[Uz|Ur]->C2
  gemm8_k<<<dim3(1024), dim3(512), 0, stream>>>(hbf, wzr, C1, xbf, uzr, C2,
                                                1024, 2048, 3, 512);

  epi1_k<<<dim3(4096), dim3(256), 0, stream>>>(C1, C2, hbf, xbf /*rph out*/,
                                               b_z, b_r, h_n, x_n, rph_n);

  // Mh = rph @ Wh : A = xbf (tight lda=1024), C -> C2 hi half (over dead Mr_x)
  gemm8_k<<<dim3(256), dim3(512), 0, stream>>>(xbf, wht, C2 + 1024,
                                               xbf, wht, C2 + 1024,
                                               1024, 2048, 2, 256);

  epi2_k<<<dim3(4096), dim3(256), 0, stream>>>(C1, C2, hbf, b_h, rph_n, out);
}